// Round 7
// baseline (24.832 us; speedup 1.0000x reference)
//
#include <hip/hip_runtime.h>

using uint = unsigned int;

// ws dword layout (spn-visible table in [0, DW_TOT))
#define DW_LO    0        // [7][16v][16oc][4] bf16-pairs lo (k0..7), v-stride 68, p-stride 1088
#define DW_HIb   7616     // hi (k8..15)
#define DW_FT    15232    // [8][16] f32 final-triple vectors
#define DW_DELTA 15360    // [32] f32 bm[v][1]-bm[v][0]
#define DW_BASE  15392    // [1]  sum bm[v][0]
#define DW_EB0   15396    // [2][16] f32 normalized var-0 leaf
#define DW_TOT   15616    // 62.5 KB
// intermediate (K1 -> K2)
#define WFW      16384    // [30][2][16][16] f32 folded per-step weights
#define WLW      31744    // [2][16] f32 folded last-step vectors

template<int K>
__device__ __forceinline__ int roti(int x) {
    return __builtin_amdgcn_update_dpp(0, x, 0x120 | K, 0xF, 0xF, true); // row_ror:K
}
template<int K>
__device__ __forceinline__ float rotf(float x) {
    return __builtin_bit_cast(float, roti<K>(__builtin_bit_cast(int, x)));
}
__device__ __forceinline__ float rowmax16(float d) {
    d = fmaxf(d, rotf<1>(d)); d = fmaxf(d, rotf<2>(d));
    d = fmaxf(d, rotf<4>(d)); d = fmaxf(d, rotf<8>(d));
    return d;
}
__device__ __forceinline__ float rowsum16(float d) {
    d += rotf<1>(d); d += rotf<2>(d); d += rotf<4>(d); d += rotf<8>(d);
    return d;
}
__device__ __forceinline__ float logsig(float z) {
    return fminf(z, 0.f) - log1pf(__expf(-fabsf(z)));
}
__device__ __forceinline__ uint bfpack(float a, float b) { // RNE pack, a->lo, b->hi
    uint ua = __builtin_bit_cast(uint, a);
    uint ub = __builtin_bit_cast(uint, b);
    ua = (ua + 0x7fffu + ((ua >> 16) & 1u)) >> 16;
    ub = ((ub + 0x7fffu + ((ub >> 16) & 1u)) >> 16) << 16;
    return ua | ub;
}
__device__ __forceinline__ float blo(uint u) { return __builtin_bit_cast(float, u << 16); }
__device__ __forceinline__ float bhi(uint u) { return __builtin_bit_cast(float, u & 0xffff0000u); }
__device__ __forceinline__ unsigned spread16(unsigned u) { // bit k -> bit 2k
    u = (u | (u << 8)) & 0x00FF00FFu;
    u = (u | (u << 4)) & 0x0F0F0F0Fu;
    u = (u | (u << 2)) & 0x33333333u;
    u = (u | (u << 1)) & 0x55555555u;
    return u;
}

// ---------------- K1: per-step folded weights Wf (30 blocks) + scalars (block 30) ----------------
__global__ __launch_bounds__(256) void prep1(const float* __restrict__ sw,
                                             const float* __restrict__ swl,
                                             const float* __restrict__ ll,
                                             float* __restrict__ ws) {
    __shared__ float pm[256];
    __shared__ float ebs[32];
    __shared__ float BMs[64];
    const int tid = threadIdx.x;
    const int c = blockIdx.x;
    const int i = tid >> 4, oc = tid & 15;

    if (c < 30) {
        if (tid < 32) {  // eb for var c+1, both bits
            int bb = tid >> 4;
            float l = ll[(c + 1) * 16 + oc];
            float lp = bb ? logsig(l) : logsig(-l);
            ebs[tid] = __expf(lp - rowmax16(lp));
        }
        const float* Wb = sw + c * 4096;
        float w[16]; float m = -1e30f;
        #pragma unroll
        for (int j = 0; j < 16; ++j) {
            w[j] = Wb[i * 256 + j * 16 + oc];
            m = fmaxf(m, w[j]);
        }
        pm[i * 16 + oc] = m;
        __syncthreads();
        float cm = pm[oc];
        #pragma unroll
        for (int r = 1; r < 16; ++r) cm = fmaxf(cm, pm[r * 16 + oc]);
        float e[16]; float s = 0.f;
        #pragma unroll
        for (int j = 0; j < 16; ++j) { e[j] = __expf(w[j] - cm); s += e[j]; }
        __syncthreads();
        pm[i * 16 + oc] = s;
        __syncthreads();
        float ss = pm[oc];
        #pragma unroll
        for (int r = 1; r < 16; ++r) ss += pm[r * 16 + oc];
        float inv = 1.0f / ss;
        float a0 = 0.f, a1 = 0.f;
        #pragma unroll
        for (int j = 0; j < 16; ++j) { a0 += ebs[j] * e[j]; a1 += ebs[16 + j] * e[j]; }
        ws[WFW + ((c * 2 + 0) * 16 + i) * 16 + oc] = a0 * inv;
        ws[WFW + ((c * 2 + 1) * 16 + i) * 16 + oc] = a1 * inv;
    } else {
        // last column softmax (256 x 1) + WL + BM/delta/base + EB0
        float v = swl[tid];
        float m = v;
        #pragma unroll
        for (int off = 32; off >= 1; off >>= 1) m = fmaxf(m, __shfl_xor(m, off));
        if ((tid & 63) == 0) pm[tid >> 6] = m;
        if (tid < 32) {  // eb for var 31
            int bb = tid >> 4;
            float l = ll[31 * 16 + oc];
            float lp = bb ? logsig(l) : logsig(-l);
            ebs[tid] = __expf(lp - rowmax16(lp));
        }
        __syncthreads();
        m = fmaxf(fmaxf(pm[0], pm[1]), fmaxf(pm[2], pm[3]));
        float e = __expf(v - m);
        float s = e;
        #pragma unroll
        for (int off = 32; off >= 1; off >>= 1) s += __shfl_xor(s, off);
        __syncthreads();
        if ((tid & 63) == 0) pm[tid >> 6] = s;
        __syncthreads();
        float inv = 1.0f / (pm[0] + pm[1] + pm[2] + pm[3]);
        // WL[b][i] = sum_j eb[b][j] * eL[i*16+j] (lane oc holds j=oc of row i)
        float t0 = rowsum16(ebs[oc] * e);
        float t1 = rowsum16(ebs[16 + oc] * e);
        if (oc == 0) {
            ws[WLW + 0 + i]  = t0 * inv;
            ws[WLW + 16 + i] = t1 * inv;
        }
        if (tid < 64) {  // BM[var][b]
            int var = tid >> 1, bb = tid & 1;
            float mm_ = -1e30f;
            #pragma unroll
            for (int j = 0; j < 16; ++j) {
                float l = ll[var * 16 + j];
                mm_ = fmaxf(mm_, bb ? logsig(l) : logsig(-l));
            }
            BMs[tid] = mm_;
        }
        if (tid >= 64 && tid < 96) {  // EB0
            int u = tid - 64, bb = u >> 4, j = u & 15;
            float mm_ = -1e30f;
            #pragma unroll
            for (int jj = 0; jj < 16; ++jj) {
                float l = ll[jj];
                mm_ = fmaxf(mm_, bb ? logsig(l) : logsig(-l));
            }
            float l = ll[j];
            ws[DW_EB0 + u] = __expf((bb ? logsig(l) : logsig(-l)) - mm_);
        }
        __syncthreads();
        if (tid < 32) ws[DW_DELTA + tid] = BMs[2 * tid + 1] - BMs[2 * tid];
        if (tid < 64) {
            float vb = (tid < 32) ? BMs[2 * tid] : 0.f;
            #pragma unroll
            for (int off = 32; off >= 1; off >>= 1) vb += __shfl_xor(vb, off);
            if (tid == 0) ws[DW_BASE] = vb;
        }
    }
}

// ---------------- K2: quad products via DPP-rotation dots (blocks 0..6) + final triple (block 7) ----
__global__ __launch_bounds__(256) void prep2(float* __restrict__ ws) {
    __shared__ __align__(16) float WFs[2048];
    __shared__ float Ts[1024];
    __shared__ float Ms[4096];
    const int tid = threadIdx.x;
    const int p = blockIdx.x;
    const int i = tid >> 4, oc = tid & 15;

    // derive row_ror permutation empirically (must match quadstep in spn_main)
    int s1 = roti<1>(oc) & 15,   s2 = roti<2>(oc) & 15,   s3 = roti<3>(oc) & 15;
    int s4 = roti<4>(oc) & 15,   s5 = roti<5>(oc) & 15,   s6 = roti<6>(oc) & 15;
    int s7 = roti<7>(oc) & 15,   s8 = roti<8>(oc) & 15,   s9 = roti<9>(oc) & 15;
    int s10 = roti<10>(oc) & 15, s11 = roti<11>(oc) & 15, s12 = roti<12>(oc) & 15;
    int s13 = roti<13>(oc) & 15, s14 = roti<14>(oc) & 15, s15 = roti<15>(oc) & 15;
    int sidx[16] = {oc, s1, s2, s3, s4, s5, s6, s7, s8, s9, s10, s11, s12, s13, s14, s15};

    if (p < 7) {
        const float4* src = (const float4*)(ws + WFW + p * 2048);
        ((float4*)WFs)[tid]       = src[tid];
        ((float4*)WFs)[256 + tid] = src[256 + tid];
        __syncthreads();

        float wf0[2], wf2[2];
        wf0[0] = WFs[0 * 256 + i * 16 + oc];
        wf0[1] = WFs[1 * 256 + i * 16 + oc];
        wf2[0] = WFs[4 * 256 + i * 16 + oc];
        wf2[1] = WFs[5 * 256 + i * 16 + oc];

        // T1[b12] = sum_k Wf0[b1][i][k]*Wf1[b2][k][oc];  T2[b34] likewise from Wf2,Wf3
        float t1[4], t2[4];
        {
            float w10 = WFs[2 * 256 + oc * 16 + oc], w11 = WFs[3 * 256 + oc * 16 + oc];
            float w30 = WFs[6 * 256 + oc * 16 + oc], w31 = WFs[7 * 256 + oc * 16 + oc];
            t1[0] = wf0[0] * w10; t1[1] = wf0[1] * w10;
            t1[2] = wf0[0] * w11; t1[3] = wf0[1] * w11;
            t2[0] = wf2[0] * w30; t2[1] = wf2[1] * w30;
            t2[2] = wf2[0] * w31; t2[3] = wf2[1] * w31;
        }
        #define QSTEP(T) { \
            float r0 = rotf<T>(wf0[0]), r1 = rotf<T>(wf0[1]); \
            float w10 = WFs[2 * 256 + sidx[T] * 16 + oc], w11 = WFs[3 * 256 + sidx[T] * 16 + oc]; \
            t1[0] = fmaf(r0, w10, t1[0]); t1[1] = fmaf(r1, w10, t1[1]); \
            t1[2] = fmaf(r0, w11, t1[2]); t1[3] = fmaf(r1, w11, t1[3]); \
            float q0 = rotf<T>(wf2[0]), q1 = rotf<T>(wf2[1]); \
            float w30 = WFs[6 * 256 + sidx[T] * 16 + oc], w31 = WFs[7 * 256 + sidx[T] * 16 + oc]; \
            t2[0] = fmaf(q0, w30, t2[0]); t2[1] = fmaf(q1, w30, t2[1]); \
            t2[2] = fmaf(q0, w31, t2[2]); t2[3] = fmaf(q1, w31, t2[3]); }
        QSTEP(1) QSTEP(2) QSTEP(3) QSTEP(4) QSTEP(5) QSTEP(6) QSTEP(7) QSTEP(8)
        QSTEP(9) QSTEP(10) QSTEP(11) QSTEP(12) QSTEP(13) QSTEP(14) QSTEP(15)
        #undef QSTEP

        #pragma unroll
        for (int b = 0; b < 4; ++b) Ts[b * 256 + i * 16 + oc] = t2[b];
        __syncthreads();

        // M[v] = sum_k T1[v&3][i][k] * T2[v>>2][k][oc]
        float M[16];
        {
            float c0 = Ts[0 * 256 + oc * 16 + oc], c1 = Ts[1 * 256 + oc * 16 + oc];
            float c2 = Ts[2 * 256 + oc * 16 + oc], c3 = Ts[3 * 256 + oc * 16 + oc];
            #pragma unroll
            for (int b12 = 0; b12 < 4; ++b12) {
                M[b12 + 0]  = t1[b12] * c0;
                M[b12 + 4]  = t1[b12] * c1;
                M[b12 + 8]  = t1[b12] * c2;
                M[b12 + 12] = t1[b12] * c3;
            }
        }
        #define MSTEP(T) { \
            float c0 = Ts[0 * 256 + sidx[T] * 16 + oc], c1 = Ts[1 * 256 + sidx[T] * 16 + oc]; \
            float c2 = Ts[2 * 256 + sidx[T] * 16 + oc], c3 = Ts[3 * 256 + sidx[T] * 16 + oc]; \
            float r0 = rotf<T>(t1[0]), r1 = rotf<T>(t1[1]), r2 = rotf<T>(t1[2]), r3 = rotf<T>(t1[3]); \
            M[0]  = fmaf(r0, c0, M[0]);  M[1]  = fmaf(r1, c0, M[1]); \
            M[2]  = fmaf(r2, c0, M[2]);  M[3]  = fmaf(r3, c0, M[3]); \
            M[4]  = fmaf(r0, c1, M[4]);  M[5]  = fmaf(r1, c1, M[5]); \
            M[6]  = fmaf(r2, c1, M[6]);  M[7]  = fmaf(r3, c1, M[7]); \
            M[8]  = fmaf(r0, c2, M[8]);  M[9]  = fmaf(r1, c2, M[9]); \
            M[10] = fmaf(r2, c2, M[10]); M[11] = fmaf(r3, c2, M[11]); \
            M[12] = fmaf(r0, c3, M[12]); M[13] = fmaf(r1, c3, M[13]); \
            M[14] = fmaf(r2, c3, M[14]); M[15] = fmaf(r3, c3, M[15]); }
        MSTEP(1) MSTEP(2) MSTEP(3) MSTEP(4) MSTEP(5) MSTEP(6) MSTEP(7) MSTEP(8)
        MSTEP(9) MSTEP(10) MSTEP(11) MSTEP(12) MSTEP(13) MSTEP(14) MSTEP(15)
        #undef MSTEP

        #pragma unroll
        for (int v = 0; v < 16; ++v) Ms[v * 256 + i * 16 + oc] = M[v];
        __syncthreads();

        // permuted bf16 pack -> ws (identical to round-5 layout)
        {
            int v = i, ocx = oc;
            const float* m = Ms + v * 256;
            float x0 = m[ocx * 16 + ocx];
            float x1 = m[s1 * 16 + ocx],   x2 = m[s2 * 16 + ocx],   x3 = m[s3 * 16 + ocx];
            float x4 = m[s4 * 16 + ocx],   x5 = m[s5 * 16 + ocx],   x6 = m[s6 * 16 + ocx];
            float x7 = m[s7 * 16 + ocx],   x8 = m[s8 * 16 + ocx],   x9 = m[s9 * 16 + ocx];
            float x10 = m[s10 * 16 + ocx], x11 = m[s11 * 16 + ocx], x12 = m[s12 * 16 + ocx];
            float x13 = m[s13 * 16 + ocx], x14 = m[s14 * 16 + ocx], x15 = m[s15 * 16 + ocx];
            uint4 lo4, hi4;
            lo4.x = bfpack(x0, x1);   lo4.y = bfpack(x2, x3);
            lo4.z = bfpack(x4, x5);   lo4.w = bfpack(x6, x7);
            hi4.x = bfpack(x8, x9);   hi4.y = bfpack(x10, x11);
            hi4.z = bfpack(x12, x13); hi4.w = bfpack(x14, x15);
            uint* wsu = (uint*)ws;
            int dw = p * 1088 + v * 68 + ocx * 4;
            *(uint4*)(wsu + dw) = lo4;
            *(uint4*)(wsu + DW_HIb + dw) = hi4;
        }
    } else {
        // final triple: t01 = Wf28_b0 * Wf29_b1 (rotation dot), FT[v][i] = t01[v&3][i] . WL[v>>2]
        const float4* src = (const float4*)(ws + WFW + 28 * 512);
        ((float4*)WFs)[tid] = src[tid];   // 1024 dw: Wf28[b], Wf29[b]
        __syncthreads();

        float wf28[2];
        wf28[0] = WFs[0 * 256 + i * 16 + oc];
        wf28[1] = WFs[1 * 256 + i * 16 + oc];
        float t01[4];
        {
            float w0 = WFs[2 * 256 + oc * 16 + oc], w1 = WFs[3 * 256 + oc * 16 + oc];
            t01[0] = wf28[0] * w0; t01[1] = wf28[1] * w0;
            t01[2] = wf28[0] * w1; t01[3] = wf28[1] * w1;
        }
        #define FSTEP(T) { \
            float r0 = rotf<T>(wf28[0]), r1 = rotf<T>(wf28[1]); \
            float w0 = WFs[2 * 256 + sidx[T] * 16 + oc], w1 = WFs[3 * 256 + sidx[T] * 16 + oc]; \
            t01[0] = fmaf(r0, w0, t01[0]); t01[1] = fmaf(r1, w0, t01[1]); \
            t01[2] = fmaf(r0, w1, t01[2]); t01[3] = fmaf(r1, w1, t01[3]); }
        FSTEP(1) FSTEP(2) FSTEP(3) FSTEP(4) FSTEP(5) FSTEP(6) FSTEP(7) FSTEP(8)
        FSTEP(9) FSTEP(10) FSTEP(11) FSTEP(12) FSTEP(13) FSTEP(14) FSTEP(15)
        #undef FSTEP

        float wl0 = ws[WLW + oc], wl1 = ws[WLW + 16 + oc];
        #pragma unroll
        for (int v = 0; v < 8; ++v) {
            float f = rowsum16(t01[v & 3] * ((v >> 2) ? wl1 : wl0));
            if (oc == 0) ws[DW_FT + v * 16 + i] = f;
        }
    }
}

// ---------------- spn_main: identical to round 5 (verified) ----------------
__device__ __forceinline__ float quadstep(const uint* sPT, float acc, int dw) {
    uint4 wl4 = *(const uint4*)(sPT + dw);
    uint4 wh4 = *(const uint4*)(sPT + DW_HIb + dw);
    float d0 = acc * blo(wl4.x);
    d0 = fmaf(rotf<1>(acc), bhi(wl4.x), d0);
    d0 = fmaf(rotf<2>(acc), blo(wl4.y), d0);
    d0 = fmaf(rotf<3>(acc), bhi(wl4.y), d0);
    d0 = fmaf(rotf<4>(acc), blo(wl4.z), d0);
    d0 = fmaf(rotf<5>(acc), bhi(wl4.z), d0);
    d0 = fmaf(rotf<6>(acc), blo(wl4.w), d0);
    d0 = fmaf(rotf<7>(acc), bhi(wl4.w), d0);
    float d1 = rotf<8>(acc) * blo(wh4.x);
    d1 = fmaf(rotf<9>(acc),  bhi(wh4.x), d1);
    d1 = fmaf(rotf<10>(acc), blo(wh4.y), d1);
    d1 = fmaf(rotf<11>(acc), bhi(wh4.y), d1);
    d1 = fmaf(rotf<12>(acc), blo(wh4.z), d1);
    d1 = fmaf(rotf<13>(acc), bhi(wh4.z), d1);
    d1 = fmaf(rotf<14>(acc), blo(wh4.w), d1);
    d1 = fmaf(rotf<15>(acc), bhi(wh4.w), d1);
    return d0 + d1;
}

__global__ __launch_bounds__(512, 4) void spn_main(const int* __restrict__ x,
                                                   const float* __restrict__ ws,
                                                   float* __restrict__ out) {
    __shared__ __align__(16) float sL[DW_TOT];
    const int tid = threadIdx.x;
    const int g = tid >> 4, oc = tid & 15;
    const int b0 = blockIdx.x * 64 + g;
    const int b1 = b0 + 32;

    int2 xa = *(const int2*)(x + b0 * 32 + 2 * oc);
    int2 xb = *(const int2*)(x + b1 * 32 + 2 * oc);
    unsigned long long ma0 = __ballot(xa.x & 1);
    unsigned long long ma1 = __ballot(xa.y & 1);
    unsigned long long mb0 = __ballot(xb.x & 1);
    unsigned long long mb1 = __ballot(xb.y & 1);
    const int gw = g & 3;
    unsigned bitsA = spread16((unsigned)(ma0 >> (gw * 16)) & 0xffffu)
                   | (spread16((unsigned)(ma1 >> (gw * 16)) & 0xffffu) << 1);
    unsigned bitsB = spread16((unsigned)(mb0 >> (gw * 16)) & 0xffffu)
                   | (spread16((unsigned)(mb1 >> (gw * 16)) & 0xffffu) << 1);

    for (int k = tid; k < DW_TOT / 4; k += 512)
        ((float4*)sL)[k] = ((const float4*)ws)[k];
    __syncthreads();

    float2 dl = *(const float2*)(sL + DW_DELTA + 2 * oc);
    float pa = ((xa.x & 1) ? dl.x : 0.f) + ((xa.y & 1) ? dl.y : 0.f);
    float pb = ((xb.x & 1) ? dl.x : 0.f) + ((xb.y & 1) ? dl.y : 0.f);
    float base = sL[DW_BASE];
    float LA = base + rowsum16(pa);
    float LB = base + rowsum16(pb);

    float accA = sL[DW_EB0 + (bitsA & 1) * 16 + oc];
    float accB = sL[DW_EB0 + (bitsB & 1) * 16 + oc];
    const uint* sPT = (const uint*)sL;
    const int ocd = oc * 4;

    #pragma unroll
    for (int p = 0; p < 7; ++p) {
        int dwA = p * 1088 + (int)((bitsA >> (4 * p + 1)) & 15) * 68 + ocd;
        int dwB = p * 1088 + (int)((bitsB >> (4 * p + 1)) & 15) * 68 + ocd;
        float dA = quadstep(sPT, accA, dwA);
        float dB = quadstep(sPT, accB, dwB);
        if (p & 1) {
            float mA = rowmax16(dA), mB = rowmax16(dB);
            accA = dA * __builtin_amdgcn_rcpf(mA);
            accB = dB * __builtin_amdgcn_rcpf(mB);
            LA += __logf(mA);
            LB += __logf(mB);
        } else {
            accA = dA; accB = dB;
        }
    }

    float tsA = rowsum16(accA * sL[DW_FT + ((bitsA >> 29) & 7) * 16 + oc]);
    float tsB = rowsum16(accB * sL[DW_FT + ((bitsB >> 29) & 7) * 16 + oc]);
    if (oc == 0) {
        out[b0] = LA + __logf(tsA);
        out[b1] = LB + __logf(tsB);
    }
}

extern "C" void kernel_launch(void* const* d_in, const int* in_sizes, int n_in,
                              void* d_out, int out_size, void* d_ws, size_t ws_size,
                              hipStream_t stream) {
    const int*   x   = (const int*)d_in[0];
    const float* ll  = (const float*)d_in[1];
    const float* sw  = (const float*)d_in[2];
    const float* swl = (const float*)d_in[3];
    float* out = (float*)d_out;
    float* ws  = (float*)d_ws;

    hipLaunchKernelGGL(prep1,    dim3(31),  dim3(256), 0, stream, sw, swl, ll, ws);
    hipLaunchKernelGGL(prep2,    dim3(8),   dim3(256), 0, stream, ws);
    hipLaunchKernelGGL(spn_main, dim3(512), dim3(512), 0, stream, x, ws, out);
}

// Round 8
// 22.184 us; speedup vs baseline: 1.1194x; 1.1194x over previous
//
#include <hip/hip_runtime.h>

using uint = unsigned int;

// ws dword layout (spn-visible table in [0, DW_TOT))
#define DW_LO    0        // [7][16v][16oc][4] bf16-pairs lo (k0..7), v-stride 68, p-stride 1088
#define DW_HIb   7616     // hi (k8..15)
#define DW_FT    15232    // [8][16] f32 final-triple vectors
#define DW_DELTA 15360    // [32] f32 bm[v][1]-bm[v][0]
#define DW_BASE  15392    // [1]  sum bm[v][0]
#define DW_EB0   15396    // [2][16] f32 normalized var-0 leaf
#define DW_TOT   15616    // 62.5 KB

template<int K>
__device__ __forceinline__ int roti(int x) {
    return __builtin_amdgcn_update_dpp(0, x, 0x120 | K, 0xF, 0xF, true); // row_ror:K
}
template<int K>
__device__ __forceinline__ float rotf(float x) {
    return __builtin_bit_cast(float, roti<K>(__builtin_bit_cast(int, x)));
}
__device__ __forceinline__ float rowmax16(float d) {
    d = fmaxf(d, rotf<1>(d)); d = fmaxf(d, rotf<2>(d));
    d = fmaxf(d, rotf<4>(d)); d = fmaxf(d, rotf<8>(d));
    return d;
}
__device__ __forceinline__ float rowsum16(float d) {
    d += rotf<1>(d); d += rotf<2>(d); d += rotf<4>(d); d += rotf<8>(d);
    return d;
}
__device__ __forceinline__ float logsig(float z) {
    return fminf(z, 0.f) - log1pf(__expf(-fabsf(z)));
}
__device__ __forceinline__ uint bfpack(float a, float b) { // RNE pack, a->lo, b->hi
    uint ua = __builtin_bit_cast(uint, a);
    uint ub = __builtin_bit_cast(uint, b);
    ua = (ua + 0x7fffu + ((ua >> 16) & 1u)) >> 16;
    ub = ((ub + 0x7fffu + ((ub >> 16) & 1u)) >> 16) << 16;
    return ua | ub;
}
__device__ __forceinline__ float blo(uint u) { return __builtin_bit_cast(float, u << 16); }
__device__ __forceinline__ float bhi(uint u) { return __builtin_bit_cast(float, u & 0xffff0000u); }
__device__ __forceinline__ unsigned spread16(unsigned u) { // bit k -> bit 2k
    u = (u | (u << 8)) & 0x00FF00FFu;
    u = (u | (u << 4)) & 0x0F0F0F0Fu;
    u = (u | (u << 2)) & 0x33333333u;
    u = (u | (u << 1)) & 0x55555555u;
    return u;
}

// ---------------- prep: 8 self-sufficient blocks x 512 threads ----------------
// Blocks 0..6: fold Wf for steps 4p..4p+3 from raw sw, quad product via DPP
// rotation dots, permuted bf16 pack -> ws.  Block 7: Wf28/29 + last column
// softmax + WL + final-triple FT + BM/delta/base/EB0 scalars.
__global__ __launch_bounds__(512) void prep(const float* __restrict__ sw,
                                            const float* __restrict__ swl,
                                            const float* __restrict__ ll,
                                            float* __restrict__ ws) {
    __shared__ __align__(16) float WFs[2048];  // [cb][i][oc], cb = cc*2+b
    __shared__ float pm[1024];                 // col-stat partials [cc][oc][i]
    __shared__ float CM[64], CS[64];
    __shared__ float ebs[128];                 // [cb][j]
    __shared__ float Ts[1024];                 // t2 staging
    __shared__ float Ms[4096];                 // pack staging
    __shared__ float BMs[64];
    __shared__ float WLs[32];
    __shared__ float pml[16], psl[16];
    __shared__ float CMl, CSl;

    const int tid = threadIdx.x;
    const int p = blockIdx.x;
    const int oc = tid & 15;
    const int i0 = (tid >> 4) & 15;

    // derive row_ror permutation empirically (must match quadstep in spn_main)
    int s1 = roti<1>(oc) & 15,   s2 = roti<2>(oc) & 15,   s3 = roti<3>(oc) & 15;
    int s4 = roti<4>(oc) & 15,   s5 = roti<5>(oc) & 15,   s6 = roti<6>(oc) & 15;
    int s7 = roti<7>(oc) & 15,   s8 = roti<8>(oc) & 15,   s9 = roti<9>(oc) & 15;
    int s10 = roti<10>(oc) & 15, s11 = roti<11>(oc) & 15, s12 = roti<12>(oc) & 15;
    int s13 = roti<13>(oc) & 15, s14 = roti<14>(oc) & 15, s15 = roti<15>(oc) & 15;
    int sidx[16] = {oc, s1, s2, s3, s4, s5, s6, s7, s8, s9, s10, s11, s12, s13, s14, s15};

    if (p < 7) {
        // P0: EB + raw W loads + col-max partials (2 slots/thread: cc0, cc0+2)
        if (tid < 128) {
            int cc = tid >> 5, bb = (tid >> 4) & 1, var = 4 * p + 1 + cc;
            float l = ll[var * 16 + oc];
            float lp = bb ? logsig(l) : logsig(-l);
            ebs[tid] = __expf(lp - rowmax16(lp));
        }
        const float* Wb = sw + p * 4 * 4096;
        const int cc0 = tid >> 8, cc1 = cc0 + 2;
        float w0[16], w1[16];
        float m0 = -1e30f, m1 = -1e30f;
        #pragma unroll
        for (int j = 0; j < 16; ++j) {
            w0[j] = Wb[cc0 * 4096 + (i0 * 16 + j) * 16 + oc];
            w1[j] = Wb[cc1 * 4096 + (i0 * 16 + j) * 16 + oc];
            m0 = fmaxf(m0, w0[j]); m1 = fmaxf(m1, w1[j]);
        }
        pm[cc0 * 256 + oc * 16 + i0] = m0;
        pm[cc1 * 256 + oc * 16 + i0] = m1;
        __syncthreads();
        if (tid < 64) {
            const float* q = pm + (tid >> 4) * 256 + (tid & 15) * 16;
            float m = q[0];
            #pragma unroll
            for (int r = 1; r < 16; ++r) m = fmaxf(m, q[r]);
            CM[tid] = m;
        }
        __syncthreads();
        float cm0 = CM[cc0 * 16 + oc], cm1 = CM[cc1 * 16 + oc];
        float e0[16], e1[16];
        float su0 = 0.f, su1 = 0.f;
        #pragma unroll
        for (int j = 0; j < 16; ++j) {
            e0[j] = __expf(w0[j] - cm0); su0 += e0[j];
            e1[j] = __expf(w1[j] - cm1); su1 += e1[j];
        }
        pm[cc0 * 256 + oc * 16 + i0] = su0;
        pm[cc1 * 256 + oc * 16 + i0] = su1;
        __syncthreads();
        if (tid < 64) {
            const float* q = pm + (tid >> 4) * 256 + (tid & 15) * 16;
            float s = 0.f;
            #pragma unroll
            for (int r = 0; r < 16; ++r) s += q[r];
            CS[tid] = 1.0f / s;
        }
        __syncthreads();
        {
            float inv0 = CS[cc0 * 16 + oc], inv1 = CS[cc1 * 16 + oc];
            float a00 = 0.f, a01 = 0.f, a10 = 0.f, a11 = 0.f;
            #pragma unroll
            for (int j = 0; j < 16; ++j) {
                a00 += ebs[(cc0 * 2 + 0) * 16 + j] * e0[j];
                a01 += ebs[(cc0 * 2 + 1) * 16 + j] * e0[j];
                a10 += ebs[(cc1 * 2 + 0) * 16 + j] * e1[j];
                a11 += ebs[(cc1 * 2 + 1) * 16 + j] * e1[j];
            }
            WFs[(cc0 * 2 + 0) * 256 + i0 * 16 + oc] = a00 * inv0;
            WFs[(cc0 * 2 + 1) * 256 + i0 * 16 + oc] = a01 * inv0;
            WFs[(cc1 * 2 + 0) * 256 + i0 * 16 + oc] = a10 * inv1;
            WFs[(cc1 * 2 + 1) * 256 + i0 * 16 + oc] = a11 * inv1;
        }
        __syncthreads();

        // rotation-dot quad product (first 256 threads), verbatim round-7 core
        float t1[4], t2[4];
        if (tid < 256) {
            float wf0[2], wf2[2];
            wf0[0] = WFs[0 * 256 + i0 * 16 + oc];
            wf0[1] = WFs[1 * 256 + i0 * 16 + oc];
            wf2[0] = WFs[4 * 256 + i0 * 16 + oc];
            wf2[1] = WFs[5 * 256 + i0 * 16 + oc];
            {
                float w10 = WFs[2 * 256 + oc * 16 + oc], w11 = WFs[3 * 256 + oc * 16 + oc];
                float w30 = WFs[6 * 256 + oc * 16 + oc], w31 = WFs[7 * 256 + oc * 16 + oc];
                t1[0] = wf0[0] * w10; t1[1] = wf0[1] * w10;
                t1[2] = wf0[0] * w11; t1[3] = wf0[1] * w11;
                t2[0] = wf2[0] * w30; t2[1] = wf2[1] * w30;
                t2[2] = wf2[0] * w31; t2[3] = wf2[1] * w31;
            }
            #define QSTEP(T) { \
                float r0 = rotf<T>(wf0[0]), r1 = rotf<T>(wf0[1]); \
                float w10 = WFs[2 * 256 + sidx[T] * 16 + oc], w11 = WFs[3 * 256 + sidx[T] * 16 + oc]; \
                t1[0] = fmaf(r0, w10, t1[0]); t1[1] = fmaf(r1, w10, t1[1]); \
                t1[2] = fmaf(r0, w11, t1[2]); t1[3] = fmaf(r1, w11, t1[3]); \
                float q0 = rotf<T>(wf2[0]), q1 = rotf<T>(wf2[1]); \
                float w30 = WFs[6 * 256 + sidx[T] * 16 + oc], w31 = WFs[7 * 256 + sidx[T] * 16 + oc]; \
                t2[0] = fmaf(q0, w30, t2[0]); t2[1] = fmaf(q1, w30, t2[1]); \
                t2[2] = fmaf(q0, w31, t2[2]); t2[3] = fmaf(q1, w31, t2[3]); }
            QSTEP(1) QSTEP(2) QSTEP(3) QSTEP(4) QSTEP(5) QSTEP(6) QSTEP(7) QSTEP(8)
            QSTEP(9) QSTEP(10) QSTEP(11) QSTEP(12) QSTEP(13) QSTEP(14) QSTEP(15)
            #undef QSTEP
            #pragma unroll
            for (int b = 0; b < 4; ++b) Ts[b * 256 + i0 * 16 + oc] = t2[b];
        }
        __syncthreads();
        if (tid < 256) {
            float M[16];
            {
                float c0 = Ts[0 * 256 + oc * 16 + oc], c1 = Ts[1 * 256 + oc * 16 + oc];
                float c2 = Ts[2 * 256 + oc * 16 + oc], c3 = Ts[3 * 256 + oc * 16 + oc];
                #pragma unroll
                for (int b12 = 0; b12 < 4; ++b12) {
                    M[b12 + 0]  = t1[b12] * c0;
                    M[b12 + 4]  = t1[b12] * c1;
                    M[b12 + 8]  = t1[b12] * c2;
                    M[b12 + 12] = t1[b12] * c3;
                }
            }
            #define MSTEP(T) { \
                float c0 = Ts[0 * 256 + sidx[T] * 16 + oc], c1 = Ts[1 * 256 + sidx[T] * 16 + oc]; \
                float c2 = Ts[2 * 256 + sidx[T] * 16 + oc], c3 = Ts[3 * 256 + sidx[T] * 16 + oc]; \
                float r0 = rotf<T>(t1[0]), r1 = rotf<T>(t1[1]), r2 = rotf<T>(t1[2]), r3 = rotf<T>(t1[3]); \
                M[0]  = fmaf(r0, c0, M[0]);  M[1]  = fmaf(r1, c0, M[1]); \
                M[2]  = fmaf(r2, c0, M[2]);  M[3]  = fmaf(r3, c0, M[3]); \
                M[4]  = fmaf(r0, c1, M[4]);  M[5]  = fmaf(r1, c1, M[5]); \
                M[6]  = fmaf(r2, c1, M[6]);  M[7]  = fmaf(r3, c1, M[7]); \
                M[8]  = fmaf(r0, c2, M[8]);  M[9]  = fmaf(r1, c2, M[9]); \
                M[10] = fmaf(r2, c2, M[10]); M[11] = fmaf(r3, c2, M[11]); \
                M[12] = fmaf(r0, c3, M[12]); M[13] = fmaf(r1, c3, M[13]); \
                M[14] = fmaf(r2, c3, M[14]); M[15] = fmaf(r3, c3, M[15]); }
            MSTEP(1) MSTEP(2) MSTEP(3) MSTEP(4) MSTEP(5) MSTEP(6) MSTEP(7) MSTEP(8)
            MSTEP(9) MSTEP(10) MSTEP(11) MSTEP(12) MSTEP(13) MSTEP(14) MSTEP(15)
            #undef MSTEP
            #pragma unroll
            for (int v = 0; v < 16; ++v) Ms[v * 256 + i0 * 16 + oc] = M[v];
        }
        __syncthreads();
        if (tid < 256) {   // permuted bf16 pack -> ws
            int v = i0, ocx = oc;
            const float* m = Ms + v * 256;
            float x0 = m[ocx * 16 + ocx];
            float x1 = m[s1 * 16 + ocx],   x2 = m[s2 * 16 + ocx],   x3 = m[s3 * 16 + ocx];
            float x4 = m[s4 * 16 + ocx],   x5 = m[s5 * 16 + ocx],   x6 = m[s6 * 16 + ocx];
            float x7 = m[s7 * 16 + ocx],   x8 = m[s8 * 16 + ocx],   x9 = m[s9 * 16 + ocx];
            float x10 = m[s10 * 16 + ocx], x11 = m[s11 * 16 + ocx], x12 = m[s12 * 16 + ocx];
            float x13 = m[s13 * 16 + ocx], x14 = m[s14 * 16 + ocx], x15 = m[s15 * 16 + ocx];
            uint4 lo4, hi4;
            lo4.x = bfpack(x0, x1);   lo4.y = bfpack(x2, x3);
            lo4.z = bfpack(x4, x5);   lo4.w = bfpack(x6, x7);
            hi4.x = bfpack(x8, x9);   hi4.y = bfpack(x10, x11);
            hi4.z = bfpack(x12, x13); hi4.w = bfpack(x14, x15);
            uint* wsu = (uint*)ws;
            int dw = p * 1088 + v * 68 + ocx * 4;
            *(uint4*)(wsu + dw) = lo4;
            *(uint4*)(wsu + DW_HIb + dw) = hi4;
        }
    } else {
        // ---------------- block 7 ----------------
        // P0: EB (vars 29,30,31), raw W loads for steps 28+cc, last-col max partials
        if (tid < 96) {
            int cb = tid >> 4, bb = cb & 1;
            int var = (cb < 4) ? (29 + (cb >> 1)) : 31;
            float l = ll[var * 16 + oc];
            float lp = bb ? logsig(l) : logsig(-l);
            ebs[tid] = __expf(lp - rowmax16(lp));
        }
        const int cc = tid >> 8;       // 0 -> step 28, 1 -> step 29
        float w[16]; float m0 = -1e30f;
        #pragma unroll
        for (int j = 0; j < 16; ++j) {
            w[j] = sw[(28 + cc) * 4096 + (i0 * 16 + j) * 16 + oc];
            m0 = fmaxf(m0, w[j]);
        }
        pm[cc * 256 + oc * 16 + i0] = m0;
        float vL = 0.f;
        if (tid >= 256) {
            int u = tid - 256;
            vL = swl[u];
            float pmx = rowmax16(vL);
            if ((u & 15) == 0) pml[u >> 4] = pmx;
        }
        __syncthreads();
        if (tid < 32) {
            const float* q = pm + (tid >> 4) * 256 + (tid & 15) * 16;
            float m = q[0];
            #pragma unroll
            for (int r = 1; r < 16; ++r) m = fmaxf(m, q[r]);
            CM[tid] = m;
        }
        if (tid == 256) {
            float m = pml[0];
            #pragma unroll
            for (int r = 1; r < 16; ++r) m = fmaxf(m, pml[r]);
            CMl = m;
        }
        __syncthreads();
        float cm = CM[cc * 16 + oc];
        float e[16]; float su = 0.f;
        #pragma unroll
        for (int j = 0; j < 16; ++j) { e[j] = __expf(w[j] - cm); su += e[j]; }
        pm[cc * 256 + oc * 16 + i0] = su;
        float eL = 0.f;
        if (tid >= 256) {
            int u = tid - 256;
            eL = __expf(vL - CMl);
            float ps = rowsum16(eL);
            if ((u & 15) == 0) psl[u >> 4] = ps;
        }
        __syncthreads();
        if (tid < 32) {
            const float* q = pm + (tid >> 4) * 256 + (tid & 15) * 16;
            float s = 0.f;
            #pragma unroll
            for (int r = 0; r < 16; ++r) s += q[r];
            CS[tid] = 1.0f / s;
        }
        if (tid == 256) {
            float s = 0.f;
            #pragma unroll
            for (int r = 0; r < 16; ++r) s += psl[r];
            CSl = 1.0f / s;
        }
        __syncthreads();
        // P4: fold Wf28/29 + WL + BM + EB0
        {
            float inv = CS[cc * 16 + oc];
            float a0 = 0.f, a1 = 0.f;
            #pragma unroll
            for (int j = 0; j < 16; ++j) {
                a0 += ebs[(cc * 2 + 0) * 16 + j] * e[j];
                a1 += ebs[(cc * 2 + 1) * 16 + j] * e[j];
            }
            WFs[(cc * 2 + 0) * 256 + i0 * 16 + oc] = a0 * inv;
            WFs[(cc * 2 + 1) * 256 + i0 * 16 + oc] = a1 * inv;
        }
        if (tid >= 256) {   // WL[b][i] = (sum_j eb31[b][j] * eL[i*16+j]) * CSl
            int u = tid - 256, iw = u >> 4;
            float t0 = rowsum16(ebs[64 + oc] * eL);
            float t1 = rowsum16(ebs[80 + oc] * eL);
            if (oc == 0) { WLs[iw] = t0 * CSl; WLs[16 + iw] = t1 * CSl; }
        }
        if (tid < 64) {     // BM[var][b]
            int var = tid >> 1, bb = tid & 1;
            float mm_ = -1e30f;
            #pragma unroll
            for (int j = 0; j < 16; ++j) {
                float l = ll[var * 16 + j];
                mm_ = fmaxf(mm_, bb ? logsig(l) : logsig(-l));
            }
            BMs[tid] = mm_;
        }
        if (tid >= 64 && tid < 96) {   // EB0
            int u = tid - 64, bb = u >> 4, j = u & 15;
            float mm_ = -1e30f;
            #pragma unroll
            for (int jj = 0; jj < 16; ++jj) {
                float l = ll[jj];
                mm_ = fmaxf(mm_, bb ? logsig(l) : logsig(-l));
            }
            float l = ll[j];
            ws[DW_EB0 + u] = __expf((bb ? logsig(l) : logsig(-l)) - mm_);
        }
        __syncthreads();
        // P5: final triple via rotation dots + FT, plus delta/base
        if (tid < 256) {
            float wf28[2];
            wf28[0] = WFs[0 * 256 + i0 * 16 + oc];
            wf28[1] = WFs[1 * 256 + i0 * 16 + oc];
            float t01[4];
            {
                float w0_ = WFs[2 * 256 + oc * 16 + oc], w1_ = WFs[3 * 256 + oc * 16 + oc];
                t01[0] = wf28[0] * w0_; t01[1] = wf28[1] * w0_;
                t01[2] = wf28[0] * w1_; t01[3] = wf28[1] * w1_;
            }
            #define FSTEP(T) { \
                float r0 = rotf<T>(wf28[0]), r1 = rotf<T>(wf28[1]); \
                float w0_ = WFs[2 * 256 + sidx[T] * 16 + oc], w1_ = WFs[3 * 256 + sidx[T] * 16 + oc]; \
                t01[0] = fmaf(r0, w0_, t01[0]); t01[1] = fmaf(r1, w0_, t01[1]); \
                t01[2] = fmaf(r0, w1_, t01[2]); t01[3] = fmaf(r1, w1_, t01[3]); }
            FSTEP(1) FSTEP(2) FSTEP(3) FSTEP(4) FSTEP(5) FSTEP(6) FSTEP(7) FSTEP(8)
            FSTEP(9) FSTEP(10) FSTEP(11) FSTEP(12) FSTEP(13) FSTEP(14) FSTEP(15)
            #undef FSTEP
            float wl0 = WLs[oc], wl1 = WLs[16 + oc];
            #pragma unroll
            for (int v = 0; v < 8; ++v) {
                float f = rowsum16(t01[v & 3] * ((v >> 2) ? wl1 : wl0));
                if (oc == 0) ws[DW_FT + v * 16 + i0] = f;
            }
        }
        if (tid < 32) ws[DW_DELTA + tid] = BMs[2 * tid + 1] - BMs[2 * tid];
        if (tid < 64) {
            float vb = (tid < 32) ? BMs[2 * tid] : 0.f;
            #pragma unroll
            for (int off = 32; off >= 1; off >>= 1) vb += __shfl_xor(vb, off);
            if (tid == 0) ws[DW_BASE] = vb;
        }
    }
}

// ---------------- spn_main: identical to round 5/7 (verified) ----------------
__device__ __forceinline__ float quadstep(const uint* sPT, float acc, int dw) {
    uint4 wl4 = *(const uint4*)(sPT + dw);
    uint4 wh4 = *(const uint4*)(sPT + DW_HIb + dw);
    float d0 = acc * blo(wl4.x);
    d0 = fmaf(rotf<1>(acc), bhi(wl4.x), d0);
    d0 = fmaf(rotf<2>(acc), blo(wl4.y), d0);
    d0 = fmaf(rotf<3>(acc), bhi(wl4.y), d0);
    d0 = fmaf(rotf<4>(acc), blo(wl4.z), d0);
    d0 = fmaf(rotf<5>(acc), bhi(wl4.z), d0);
    d0 = fmaf(rotf<6>(acc), blo(wl4.w), d0);
    d0 = fmaf(rotf<7>(acc), bhi(wl4.w), d0);
    float d1 = rotf<8>(acc) * blo(wh4.x);
    d1 = fmaf(rotf<9>(acc),  bhi(wh4.x), d1);
    d1 = fmaf(rotf<10>(acc), blo(wh4.y), d1);
    d1 = fmaf(rotf<11>(acc), bhi(wh4.y), d1);
    d1 = fmaf(rotf<12>(acc), blo(wh4.z), d1);
    d1 = fmaf(rotf<13>(acc), bhi(wh4.z), d1);
    d1 = fmaf(rotf<14>(acc), blo(wh4.w), d1);
    d1 = fmaf(rotf<15>(acc), bhi(wh4.w), d1);
    return d0 + d1;
}

__global__ __launch_bounds__(512, 4) void spn_main(const int* __restrict__ x,
                                                   const float* __restrict__ ws,
                                                   float* __restrict__ out) {
    __shared__ __align__(16) float sL[DW_TOT];
    const int tid = threadIdx.x;
    const int g = tid >> 4, oc = tid & 15;
    const int b0 = blockIdx.x * 64 + g;
    const int b1 = b0 + 32;

    int2 xa = *(const int2*)(x + b0 * 32 + 2 * oc);
    int2 xb = *(const int2*)(x + b1 * 32 + 2 * oc);
    unsigned long long ma0 = __ballot(xa.x & 1);
    unsigned long long ma1 = __ballot(xa.y & 1);
    unsigned long long mb0 = __ballot(xb.x & 1);
    unsigned long long mb1 = __ballot(xb.y & 1);
    const int gw = g & 3;
    unsigned bitsA = spread16((unsigned)(ma0 >> (gw * 16)) & 0xffffu)
                   | (spread16((unsigned)(ma1 >> (gw * 16)) & 0xffffu) << 1);
    unsigned bitsB = spread16((unsigned)(mb0 >> (gw * 16)) & 0xffffu)
                   | (spread16((unsigned)(mb1 >> (gw * 16)) & 0xffffu) << 1);

    for (int k = tid; k < DW_TOT / 4; k += 512)
        ((float4*)sL)[k] = ((const float4*)ws)[k];
    __syncthreads();

    float2 dl = *(const float2*)(sL + DW_DELTA + 2 * oc);
    float pa = ((xa.x & 1) ? dl.x : 0.f) + ((xa.y & 1) ? dl.y : 0.f);
    float pb = ((xb.x & 1) ? dl.x : 0.f) + ((xb.y & 1) ? dl.y : 0.f);
    float base = sL[DW_BASE];
    float LA = base + rowsum16(pa);
    float LB = base + rowsum16(pb);

    float accA = sL[DW_EB0 + (bitsA & 1) * 16 + oc];
    float accB = sL[DW_EB0 + (bitsB & 1) * 16 + oc];
    const uint* sPT = (const uint*)sL;
    const int ocd = oc * 4;

    #pragma unroll
    for (int p = 0; p < 7; ++p) {
        int dwA = p * 1088 + (int)((bitsA >> (4 * p + 1)) & 15) * 68 + ocd;
        int dwB = p * 1088 + (int)((bitsB >> (4 * p + 1)) & 15) * 68 + ocd;
        float dA = quadstep(sPT, accA, dwA);
        float dB = quadstep(sPT, accB, dwB);
        if (p & 1) {
            float mA = rowmax16(dA), mB = rowmax16(dB);
            accA = dA * __builtin_amdgcn_rcpf(mA);
            accB = dB * __builtin_amdgcn_rcpf(mB);
            LA += __logf(mA);
            LB += __logf(mB);
        } else {
            accA = dA; accB = dB;
        }
    }

    float tsA = rowsum16(accA * sL[DW_FT + ((bitsA >> 29) & 7) * 16 + oc]);
    float tsB = rowsum16(accB * sL[DW_FT + ((bitsB >> 29) & 7) * 16 + oc]);
    if (oc == 0) {
        out[b0] = LA + __logf(tsA);
        out[b1] = LB + __logf(tsB);
    }
}

extern "C" void kernel_launch(void* const* d_in, const int* in_sizes, int n_in,
                              void* d_out, int out_size, void* d_ws, size_t ws_size,
                              hipStream_t stream) {
    const int*   x   = (const int*)d_in[0];
    const float* ll  = (const float*)d_in[1];
    const float* sw  = (const float*)d_in[2];
    const float* swl = (const float*)d_in[3];
    float* out = (float*)d_out;
    float* ws  = (float*)d_ws;

    hipLaunchKernelGGL(prep,     dim3(8),   dim3(512), 0, stream, sw, swl, ll, ws);
    hipLaunchKernelGGL(spn_main, dim3(512), dim3(512), 0, stream, x, ws, out);
}